// Round 18
// baseline (123.746 us; speedup 1.0000x reference)
//
#include <hip/hip_runtime.h>
#include <hip/hip_bf16.h>

typedef unsigned short u16;
typedef __bf16 bf16x8 __attribute__((ext_vector_type(8)));
typedef float f32x4 __attribute__((ext_vector_type(4)));
typedef float f32x16 __attribute__((ext_vector_type(16)));
typedef unsigned short ushort8 __attribute__((ext_vector_type(8)));

#define C_IN   128
#define C_OUT  256
#define BATCH  16
#define LEN    4096
#define KS     9
#define PAD    4
#define KTOT   (C_IN * KS)        // 1152
#define NSTEP  72                 // K = 1152 / 16

#define W5_BLKS    1152           // 294912 / 256
#define EB_BLKS    256

__device__ inline u16 f2bf(float f) {
    __hip_bfloat16 h = __float2bfloat16(f);
    return __builtin_bit_cast(u16, h);
}

// ---------------------------------------------------------------------------
// Prep (unchanged): w5 repack + ebias + phys.
// ---------------------------------------------------------------------------
__global__ void prep_all(const float* __restrict__ w,
                         const float* __restrict__ bias, const float* __restrict__ vel,
                         const float* __restrict__ acc_in,
                         u16* __restrict__ w5,
                         float* __restrict__ ebias, float* __restrict__ phys_out) {
    int bid = blockIdx.x;
    int t = threadIdx.x;
    if (bid < W5_BLKS) {
        int i = bid * 256 + t;               // 294912 total
        int e    = i & 7;
        int lane = (i >> 3) & 63;
        int g    = (i >> 9) & 7;
        int s    = i >> 12;                  // 0..71
        int o    = g * 32 + (lane & 31);
        int hi   = lane >> 5;
        int c    = (s & 7) * 16 + hi * 8 + e;
        int k    = s >> 3;
        w5[i] = f2bf(w[((size_t)o * C_IN + c) * KS + k]);
        return;
    }
    __shared__ float red[256];
    int o = bid - W5_BLKS;
    float sum = 0.f;
    for (int i = t; i < KTOT; i += 256) {
        int k = i % KS;                    // offset layout [c][k]
        float tk = k * 0.01f;              // DT
        float off = vel[i] * tk + 0.5f * acc_in[i] * tk * tk;
        sum += off * w[(size_t)o * KTOT + i];
    }
    red[t] = sum;
    __syncthreads();
    for (int h = 128; h > 0; h >>= 1) {
        if (t < h) red[t] += red[t + h];
        __syncthreads();
    }
    if (t == 0) ebias[o] = bias[o] + red[0];

    if (o == 0) {                          // phys
        __syncthreads();
        float pv = 0.f;
        for (int i = t; i < KTOT; i += 256) {
            float v = vel[i], a = acc_in[i];
            pv += v * v + a * a;
        }
        red[t] = pv;
        __syncthreads();
        for (int h = 128; h > 0; h >>= 1) {
            if (t < h) red[t] += red[t + h];
            __syncthreads();
        }
        if (t == 0) *phys_out = 0.01f * (red[0] / (float)KTOT);
    }
}

// ---------------------------------------------------------------------------
// run_pass<MI0,NJ0,...>: one 64o x 64l sub-pass of the 128o x 128l wave tile
// (mi-pair {MI0,MI0+1} x nj-pair {NJ0,NJ0+1}), K=1152 fully accumulated.
// While computing, streams out the PREVIOUS pass's 64 outputs (1 store/step,
// issued AFTER this step's A-prefetch so the A-wait at step S only requires
// stores <= S-4 to retire -> store drain is BW-paced under the MFMA clusters
// instead of a chip-synchronized terminal burst (the 41.5us wall).
// A: global->reg ring-4, distance 3 (2 contiguous 1KB loads/step, L2-hot;
//    consecutive passes share the A range). B: ds_read dbuf distance 1.
// ---------------------------------------------------------------------------
template<int MI0, int NJ0, int HASPRV, int PMI0, int PNJ0>
__device__ __forceinline__ void run_pass(const u16* __restrict__ wlane,
                                         const char* ldsbase,
                                         float* __restrict__ outb,
                                         const float* __restrict__ ebias,
                                         int wm, int hi, int l31,
                                         f32x16 (&acc)[2][2],
                                         f32x16 (&prv)[2][2]) {
    f32x4 eb[2][4];
    if constexpr (HASPRV) {
        #pragma unroll
        for (int mi = 0; mi < 2; ++mi)
            #pragma unroll
            for (int q = 0; q < 4; ++q)
                eb[mi][q] = *reinterpret_cast<const f32x4*>(
                    ebias + wm * 128 + (PMI0 + mi) * 32 + hi * 4 + q * 8);
    }
    #pragma unroll
    for (int mi = 0; mi < 2; ++mi)
        #pragma unroll
        for (int nj = 0; nj < 2; ++nj)
            acc[mi][nj] = 0.0f;

    const u16* wp = wlane + (size_t)(wm * 4 + MI0) * 512;
    bf16x8 ar[4][2], br[2][2];
    #pragma unroll
    for (int s0 = 0; s0 < 3; ++s0) {       // ring fill: A(0..2)
        ar[s0][0] = *reinterpret_cast<const bf16x8*>(wp + (size_t)s0 * 4096);
        ar[s0][1] = *reinterpret_cast<const bf16x8*>(wp + (size_t)s0 * 4096 + 512);
    }
    {   // B(0)
        #pragma unroll
        for (int nj = 0; nj < 2; ++nj) {
            int row_ = (NJ0 + nj) * 32 + l31;
            int addr_ = row_ * 256 + ((hi ^ (row_ & 15)) << 4);
            br[0][nj] = *reinterpret_cast<const bf16x8*>(ldsbase + addr_);
        }
    }
    #pragma unroll
    for (int S = 0; S < NSTEP; ++S) {
        if (S + 3 < NSTEP) {               // A prefetch distance 3, ring 4
            ar[(S + 3) & 3][0] = *reinterpret_cast<const bf16x8*>(wp + (size_t)(S + 3) * 4096);
            ar[(S + 3) & 3][1] = *reinterpret_cast<const bf16x8*>(wp + (size_t)(S + 3) * 4096 + 512);
        }
        if constexpr (HASPRV) {            // stream prev-pass output, 1/step
            if (S < 64) {
                int mi = (S >> 5) & 1, nj = (S >> 4) & 1, q = (S >> 2) & 3, p = S & 3;
                outb[(size_t)(wm * 128 + (PMI0 + mi) * 32 + hi * 4 + q * 8 + p) * LEN
                     + (PNJ0 + nj) * 32 + l31] = prv[mi][nj][q * 4 + p] + eb[mi][q][p];
            }
        }
        if (S + 1 < NSTEP) {               // B prefetch distance 1
            int k_ = (S + 1) >> 3;
            int sl_ = ((S + 1) & 7) * 2 + hi;
            #pragma unroll
            for (int nj = 0; nj < 2; ++nj) {
                int row_ = (NJ0 + nj) * 32 + l31 + k_;
                int addr_ = row_ * 256 + ((sl_ ^ (row_ & 15)) << 4);
                br[(S + 1) & 1][nj] = *reinterpret_cast<const bf16x8*>(ldsbase + addr_);
            }
        }
        #pragma unroll
        for (int mi = 0; mi < 2; ++mi)
            #pragma unroll
            for (int nj = 0; nj < 2; ++nj)
                acc[mi][nj] = __builtin_amdgcn_mfma_f32_32x32x16_bf16(
                    ar[S & 3][mi], br[S & 1][nj], acc[mi][nj], 0, 0, 0);
    }
}

// ---------------------------------------------------------------------------
// Main: R15 fused-transpose fat-wave base, restructured into 4 sub-passes
// with store-streaming (write-burst fix). Wave tile 128o x 128l total;
// block = 2 waves = 256o x 128l; grid 512; 1 wave/SIMD.
// ---------------------------------------------------------------------------
__global__ __launch_bounds__(128, 1) void conv_main(const float* __restrict__ x,
                                                    const u16* __restrict__ w5,
                                                    const float* __restrict__ ebias,
                                                    float* __restrict__ out) {
    __shared__ u16 ldsx[17408];            // B tile: 136 rows x 256B = 34816 B

    int b     = blockIdx.y;
    int lbase = blockIdx.x * 128;
    int t     = threadIdx.x;               // 0..127
    int lane  = t & 63;
    int wm    = t >> 6;                    // wave = o-half (128 o each)
    int l31   = lane & 31;
    int hi    = lane >> 5;

    // ---- fused B-tile transpose+cast+swizzle (unchanged from R15) ----
    const float* xb = x + (size_t)b * C_IN * LEN;
    {
        int r = t;
        int l = lbase + r - PAD;
        l = l < 0 ? 0 : (l > LEN - 1 ? LEN - 1 : l);
        int key = r & 15;
        float v[16][8];
        #pragma unroll
        for (int cb = 0; cb < 16; ++cb)
            #pragma unroll
            for (int e = 0; e < 8; ++e)
                v[cb][e] = xb[(size_t)(cb * 8 + e) * LEN + l];   // coalesced
        #pragma unroll
        for (int cb = 0; cb < 16; ++cb) {
            ushort8 u;
            #pragma unroll
            for (int e = 0; e < 8; ++e) u[e] = f2bf(v[cb][e]);
            *reinterpret_cast<ushort8*>(ldsx + r * 128 + ((cb ^ key) * 8)) = u;
        }
    }
    {
        int r  = 128 + (t & 7);
        int cb = t >> 3;                   // 0..15
        int l = lbase + r - PAD;
        l = l < 0 ? 0 : (l > LEN - 1 ? LEN - 1 : l);
        ushort8 u;
        #pragma unroll
        for (int e = 0; e < 8; ++e)
            u[e] = f2bf(xb[(size_t)(cb * 8 + e) * LEN + l]);
        *reinterpret_cast<ushort8*>(ldsx + r * 128 + ((cb ^ (r & 15)) * 8)) = u;
    }
    __syncthreads();                       // B-tile ready; the only barrier

    const char* ldsbase = reinterpret_cast<const char*>(ldsx);
    const u16* wlane = w5 + lane * 8;
    float* outb = out + (size_t)b * C_OUT * LEN + lbase;

    f32x16 accA[2][2], accB[2][2];
    run_pass<0, 0, 0, 0, 0>(wlane, ldsbase, outb, ebias, wm, hi, l31, accA, accB);
    run_pass<0, 2, 1, 0, 0>(wlane, ldsbase, outb, ebias, wm, hi, l31, accB, accA);
    run_pass<2, 0, 1, 0, 2>(wlane, ldsbase, outb, ebias, wm, hi, l31, accA, accB);
    run_pass<2, 2, 1, 2, 0>(wlane, ldsbase, outb, ebias, wm, hi, l31, accB, accA);

    // ---- tail: store last pass (mi {2,3} x nj {2,3}) — only 1/4 burst naked
    #pragma unroll
    for (int mi = 0; mi < 2; ++mi) {
        int o0 = wm * 128 + (2 + mi) * 32 + hi * 4;
        #pragma unroll
        for (int nj = 0; nj < 2; ++nj) {
            int l = lbase + (2 + nj) * 32 + l31;
            #pragma unroll
            for (int q = 0; q < 4; ++q) {
                f32x4 eb = *reinterpret_cast<const f32x4*>(ebias + o0 + q * 8);
                float* op = out + (size_t)(b * C_OUT + o0 + q * 8) * LEN + l;
                #pragma unroll
                for (int p = 0; p < 4; ++p)
                    op[(size_t)p * LEN] = accB[mi][nj][q * 4 + p] + eb[p];
            }
        }
    }
}

extern "C" void kernel_launch(void* const* d_in, const int* in_sizes, int n_in,
                              void* d_out, int out_size, void* d_ws, size_t ws_size,
                              hipStream_t stream) {
    const float* x      = (const float*)d_in[0];
    const float* weight = (const float*)d_in[1];
    const float* bias   = (const float*)d_in[2];
    const float* vel    = (const float*)d_in[3];
    const float* acc    = (const float*)d_in[4];
    float* out = (float*)d_out;

    char* ws = (char*)d_ws;
    u16*  w5    = (u16*)ws;                                   // 589,824 B
    float* ebias = (float*)(ws + (size_t)C_OUT * KTOT * 2);

    hipLaunchKernelGGL(prep_all, dim3(W5_BLKS + EB_BLKS), dim3(256), 0, stream,
                       weight, bias, vel, acc, w5, ebias,
                       out + (size_t)BATCH * C_OUT * LEN);
    hipLaunchKernelGGL(conv_main, dim3(LEN / 128, BATCH), dim3(128), 0, stream,
                       x, w5, ebias, out);
}

// Round 19
// 52.145 us; speedup vs baseline: 2.3731x; 2.3731x over previous
//
#include <hip/hip_runtime.h>
#include <hip/hip_bf16.h>

typedef unsigned short u16;
typedef __bf16 bf16x8 __attribute__((ext_vector_type(8)));
typedef float f32x4 __attribute__((ext_vector_type(4)));
typedef float f32x16 __attribute__((ext_vector_type(16)));
typedef unsigned short ushort8 __attribute__((ext_vector_type(8)));

#define C_IN   128
#define C_OUT  256
#define BATCH  16
#define LEN    4096
#define KS     9
#define PAD    4
#define KTOT   (C_IN * KS)        // 1152
#define NSTEP  72                 // K = 1152 / 16

#define W5_BLKS    1152           // 294912 / 256
#define EB_BLKS    256

__device__ inline u16 f2bf(float f) {
    __hip_bfloat16 h = __float2bfloat16(f);
    return __builtin_bit_cast(u16, h);
}

// ---------------------------------------------------------------------------
// Prep (small, one launch):
//  blocks [0,1152): weight -> w5 in 32-lane fragment order for
//    mfma_f32_32x32x16_bf16:  i = ((s*8 + g)*64 + lane)*8 + e  where
//    o = g*32 + (lane&31), hi = lane>>5, c = (s&7)*16 + hi*8 + e, k = s>>3.
//  blocks [1152,1408): ebias[o] = bias[o] + sum offset*W; block 1152: phys.
// ---------------------------------------------------------------------------
__global__ void prep_all(const float* __restrict__ w,
                         const float* __restrict__ bias, const float* __restrict__ vel,
                         const float* __restrict__ acc_in,
                         u16* __restrict__ w5,
                         float* __restrict__ ebias, float* __restrict__ phys_out) {
    int bid = blockIdx.x;
    int t = threadIdx.x;
    if (bid < W5_BLKS) {
        int i = bid * 256 + t;               // 294912 total
        int e    = i & 7;
        int lane = (i >> 3) & 63;
        int g    = (i >> 9) & 7;
        int s    = i >> 12;                  // 0..71
        int o    = g * 32 + (lane & 31);
        int hi   = lane >> 5;
        int c    = (s & 7) * 16 + hi * 8 + e;
        int k    = s >> 3;
        w5[i] = f2bf(w[((size_t)o * C_IN + c) * KS + k]);
        return;
    }
    __shared__ float red[256];
    int o = bid - W5_BLKS;
    float sum = 0.f;
    for (int i = t; i < KTOT; i += 256) {
        int k = i % KS;                    // offset layout [c][k]
        float tk = k * 0.01f;              // DT
        float off = vel[i] * tk + 0.5f * acc_in[i] * tk * tk;
        sum += off * w[(size_t)o * KTOT + i];
    }
    red[t] = sum;
    __syncthreads();
    for (int h = 128; h > 0; h >>= 1) {
        if (t < h) red[t] += red[t + h];
        __syncthreads();
    }
    if (t == 0) ebias[o] = bias[o] + red[0];

    if (o == 0) {                          // phys
        __syncthreads();
        float pv = 0.f;
        for (int i = t; i < KTOT; i += 256) {
            float v = vel[i], a = acc_in[i];
            pv += v * v + a * a;
        }
        red[t] = pv;
        __syncthreads();
        for (int h = 128; h > 0; h >>= 1) {
            if (t < h) red[t] += red[t + h];
            __syncthreads();
        }
        if (t == 0) *phys_out = 0.01f * (red[0] / (float)KTOT);
    }
}

// ---------------------------------------------------------------------------
// Main (FINAL = R15, session best 51.8us total): fat-wave barrier-free
// K-loop + fused x-transpose.
//  - Wave tile 128o x 128l (acc[4][4] f32x16 = 256 AGPR, VGPR 208 ->
//    1 wave/SIMD). Block = 2 waves = 256o x 128l; grid 512 = 2 blocks/CU.
//  - Fused transpose+cast+swizzle builds the B tile in-prologue straight
//    from x (saves the 35MB xt round-trip; runs at the HBM floor).
//  - A: global->reg from L2-resident w5 (4 contiguous 1KB frags/step,
//    wm-disjoint), register dbuf distance 1; B: swizzled conflict-free
//    ds_read dbuf distance 1; no mid-loop barriers (compiler emits counted
//    vmcnt/lgkmcnt before first use).
// Session evidence: 15 structural variants (LDS-A staging, counted-vmcnt
// rings, phase-barriers, 2 waves/SIMD, NT stores, store-streaming) all land
// at conv 41.5-50us =~ 930TF = the m97-class structural ceiling; the two
// accumulator-splitting attempts spilled (VGPR 256 + scratch traffic).
// This configuration is the measured optimum of the family.
// ---------------------------------------------------------------------------
__global__ __launch_bounds__(128, 1) void conv_main(const float* __restrict__ x,
                                                    const u16* __restrict__ w5,
                                                    const float* __restrict__ ebias,
                                                    float* __restrict__ out) {
    __shared__ u16 ldsx[17408];            // B tile: 136 rows x 256B = 34816 B

    int b     = blockIdx.y;
    int lbase = blockIdx.x * 128;
    int t     = threadIdx.x;               // 0..127
    int lane  = t & 63;
    int wm    = t >> 6;                    // wave = o-half (128 o each)
    int l31   = lane & 31;
    int hi    = lane >> 5;

    // A source: wave wm's 4 o-groups (g = wm*4+mi) -> contiguous 4KB/step
    const u16* alane = w5 + ((size_t)(wm * 4) * 64 + lane) * 8;

    #define LOAD_A(S, AF)                                                        \
        {                                                                        \
            const u16* p_ = alane + (size_t)(S) * 4096;                          \
            _Pragma("unroll")                                                    \
            for (int mi = 0; mi < 4; ++mi)                                       \
                AF[mi] = *reinterpret_cast<const bf16x8*>(p_ + mi * 512);        \
        }
    #define LOAD_B(S, BF)                                                        \
        {                                                                        \
            int k_ = (S) >> 3;                                                   \
            int sl_ = ((S) & 7) * 2 + hi;                                        \
            _Pragma("unroll")                                                    \
            for (int nj = 0; nj < 4; ++nj) {                                     \
                int row_  = nj * 32 + l31 + k_;                                  \
                int addr_ = row_ * 256 + ((sl_ ^ (row_ & 15)) << 4);             \
                BF[nj] = *reinterpret_cast<const bf16x8*>(ldsbase + addr_);      \
            }                                                                    \
        }
    #define MFMA16(AF, BF)                                                       \
        {                                                                        \
            _Pragma("unroll")                                                    \
            for (int mi = 0; mi < 4; ++mi)                                       \
                _Pragma("unroll")                                                \
                for (int nj = 0; nj < 4; ++nj)                                   \
                    acc[mi][nj] = __builtin_amdgcn_mfma_f32_32x32x16_bf16(       \
                        AF[mi], BF[nj], acc[mi][nj], 0, 0, 0);                   \
        }

    bf16x8 aA[4], aB[4], bA[4], bB[4];
    LOAD_A(0, aA);                         // issue A(0) first (L2 latency hidden
                                           // under the transpose below)

    // ---- fused B-tile transpose+cast+swizzle ----
    const float* xb = x + (size_t)b * C_IN * LEN;
    {
        // phase 1: rows 0..127, one row per thread; lanes = consecutive l
        int r = t;
        int l = lbase + r - PAD;
        l = l < 0 ? 0 : (l > LEN - 1 ? LEN - 1 : l);
        int key = r & 15;
        float v[16][8];
        #pragma unroll
        for (int cb = 0; cb < 16; ++cb)
            #pragma unroll
            for (int e = 0; e < 8; ++e)
                v[cb][e] = xb[(size_t)(cb * 8 + e) * LEN + l];   // coalesced
        #pragma unroll
        for (int cb = 0; cb < 16; ++cb) {
            ushort8 u;
            #pragma unroll
            for (int e = 0; e < 8; ++e) u[e] = f2bf(v[cb][e]);
            *reinterpret_cast<ushort8*>(ldsx + r * 128 + ((cb ^ key) * 8)) = u;
        }
    }
    {
        // phase 2: halo rows 128..135, (row, cblk) unit per thread
        int r  = 128 + (t & 7);
        int cb = t >> 3;                   // 0..15
        int l = lbase + r - PAD;
        l = l < 0 ? 0 : (l > LEN - 1 ? LEN - 1 : l);
        ushort8 u;
        #pragma unroll
        for (int e = 0; e < 8; ++e)
            u[e] = f2bf(xb[(size_t)(cb * 8 + e) * LEN + l]);
        *reinterpret_cast<ushort8*>(ldsx + r * 128 + ((cb ^ (r & 15)) * 8)) = u;
    }
    __syncthreads();                       // B-tile ready; the only barrier

    f32x16 acc[4][4] = {};
    const char* ldsbase = reinterpret_cast<const char*>(ldsx);
    LOAD_B(0, bA);

    #pragma unroll
    for (int s = 0; s < NSTEP; s += 2) {
        LOAD_A(s + 1, aB);
        LOAD_B(s + 1, bB);
        MFMA16(aA, bA);
        if (s + 2 < NSTEP) { LOAD_A(s + 2, aA); LOAD_B(s + 2, bA); }
        MFMA16(aB, bB);
    }

    // ---- epilogue: 32x32 D layout col = lane&31 (l), row = (reg&3)+8*(reg>>2)+4*hi
    #pragma unroll
    for (int mi = 0; mi < 4; ++mi) {
        int o0 = wm * 128 + mi * 32 + hi * 4;
        #pragma unroll
        for (int nj = 0; nj < 4; ++nj) {
            int l = lbase + nj * 32 + l31;
            #pragma unroll
            for (int q = 0; q < 4; ++q) {
                f32x4 eb = *reinterpret_cast<const f32x4*>(ebias + o0 + q * 8);
                float* op = out + (size_t)(b * C_OUT + o0 + q * 8) * LEN + l;
                #pragma unroll
                for (int p = 0; p < 4; ++p)
                    op[(size_t)p * LEN] = acc[mi][nj][q * 4 + p] + eb[p];
            }
        }
    }
    #undef LOAD_A
    #undef LOAD_B
    #undef MFMA16
}

extern "C" void kernel_launch(void* const* d_in, const int* in_sizes, int n_in,
                              void* d_out, int out_size, void* d_ws, size_t ws_size,
                              hipStream_t stream) {
    const float* x      = (const float*)d_in[0];
    const float* weight = (const float*)d_in[1];
    const float* bias   = (const float*)d_in[2];
    const float* vel    = (const float*)d_in[3];
    const float* acc    = (const float*)d_in[4];
    float* out = (float*)d_out;

    char* ws = (char*)d_ws;
    u16*  w5    = (u16*)ws;                                   // 589,824 B
    float* ebias = (float*)(ws + (size_t)C_OUT * KTOT * 2);

    hipLaunchKernelGGL(prep_all, dim3(W5_BLKS + EB_BLKS), dim3(256), 0, stream,
                       weight, bias, vel, acc, w5, ebias,
                       out + (size_t)BATCH * C_OUT * LEN);
    hipLaunchKernelGGL(conv_main, dim3(LEN / 128, BATCH), dim3(128), 0, stream,
                       x, w5, ebias, out);
}